// Round 1
// baseline (721.498 us; speedup 1.0000x reference)
//
#include <hip/hip_runtime.h>

// Downsample2d: depthwise 4x4 blur (separable taps 1/8,3/8,3/8,1/8),
// stride 2, reflect pad 1.
// x: (8,256,256,256) fp32 -> out: (8,256,128,128) fp32.
// Memory-bound: 512 MiB read + 128 MiB write -> ~107 us floor @ 6.3 TB/s.

#define K0 0.125f
#define K1 0.375f

__global__ __launch_bounds__(256) void downsample2d_kernel(
    const float* __restrict__ x, float* __restrict__ out)
{
    // Layout: 8 blocks per (b,c) plane. Within a block:
    //   tid & 31  -> which float4 column group (ow4 = 4*(tid&31), covers W=128)
    //   tid >> 5  -> which output-row pair (2 rows/thread, 8 pairs/block)
    const int tid         = threadIdx.x;
    const int lane_w      = tid & 31;
    const int pair_in_blk = tid >> 5;
    const int blk         = blockIdx.x & 7;
    const int plane       = blockIdx.x >> 3;   // b*C + c, 0..2047

    const int ow4  = lane_w << 2;              // 0,4,...,124
    const int pair = blk * 8 + pair_in_blk;    // 0..63
    const int oh0  = pair * 2;                 // even output row
    const int ir_base = 2 * oh0 - 1;           // first of 6 input rows

    const float* xp = x   + (size_t)plane * (256 * 256);
    float*       op = out + (size_t)plane * (128 * 128);

    const int c_mid = ow4 * 2;                 // aligned float4 column
    const int cl = (ow4 == 0)   ? 1   : c_mid - 1;   // reflect left edge
    const int cr = (ow4 == 124) ? 254 : c_mid + 8;   // reflect right edge

    float acc0[4] = {0.f, 0.f, 0.f, 0.f};
    float acc1[4] = {0.f, 0.f, 0.f, 0.f};
    const float kv[4] = {K0, K1, K1, K0};

    #pragma unroll
    for (int r = 0; r < 6; ++r) {
        int ir = ir_base + r;
        ir = (ir < 0) ? 1 : ((ir > 255) ? 254 : ir);   // reflect top/bottom
        const float* row = xp + ir * 256;

        float  v0 = row[cl];
        float4 a  = *(const float4*)(row + c_mid);
        float4 b  = *(const float4*)(row + c_mid + 4);
        float  v9 = row[cr];

        // horizontal blur at the 4 even input phases
        float h0 = K0*v0  + K1*a.x + K1*a.y + K0*a.z;
        float h1 = K0*a.y + K1*a.z + K1*a.w + K0*b.x;
        float h2 = K0*a.w + K1*b.x + K1*b.y + K0*b.z;
        float h3 = K0*b.y + K1*b.z + K1*b.w + K0*v9;

        if (r < 4) {            // output row oh0 uses input rows r=0..3
            float w = kv[r];
            acc0[0] += w*h0; acc0[1] += w*h1; acc0[2] += w*h2; acc0[3] += w*h3;
        }
        if (r >= 2) {           // output row oh0+1 uses input rows r=2..5
            float w = kv[r - 2];
            acc1[0] += w*h0; acc1[1] += w*h1; acc1[2] += w*h2; acc1[3] += w*h3;
        }
    }

    *(float4*)(op + (size_t)oh0       * 128 + ow4) =
        make_float4(acc0[0], acc0[1], acc0[2], acc0[3]);
    *(float4*)(op + (size_t)(oh0 + 1) * 128 + ow4) =
        make_float4(acc1[0], acc1[1], acc1[2], acc1[3]);
}

extern "C" void kernel_launch(void* const* d_in, const int* in_sizes, int n_in,
                              void* d_out, int out_size, void* d_ws, size_t ws_size,
                              hipStream_t stream) {
    const float* x = (const float*)d_in[0];
    // d_in[1] is the 4x4 kernel == outer([1/8,3/8,3/8,1/8]) exactly; taps hardcoded.
    float* out = (float*)d_out;

    const int planes = 8 * 256;            // B*C
    const int blocks = planes * 8;         // 8 blocks per plane
    downsample2d_kernel<<<blocks, 256, 0, stream>>>(x, out);
}

// Round 2
// 707.516 us; speedup vs baseline: 1.0198x; 1.0198x over previous
//
#include <hip/hip_runtime.h>

// Downsample2d: depthwise 4x4 blur (separable taps 1/8,3/8,3/8,1/8),
// stride 2, reflect pad 1.
// x: (8,256,256,256) fp32 -> out: (8,256,128,128) fp32.
// HBM floor: 512 MiB read + 128 MiB write ~= 107 us @ 6.3 TB/s.
//
// R1: LDS-staged strip. Block = 256 threads = one (plane, 16-output-row) strip.
//   - stage 34 input rows (34 KiB) into LDS with contiguous float4 loads
//   - separable compute: per-column thread walks 8 output rows, reusing
//     2 of 4 horizontal-blur values per step (18 H per 8 outputs)
//   - coalesced dword stores

#define K0 0.125f
#define K1 0.375f

__global__ __launch_bounds__(256, 4) void downsample2d_kernel(
    const float* __restrict__ x, float* __restrict__ out)
{
    __shared__ float lds[34 * 256];           // 34 input rows x 256 cols

    const int tid   = threadIdx.x;
    const int strip = blockIdx.x & 7;         // 8 strips of 16 output rows
    const int plane = blockIdx.x >> 3;        // b*C + c, 0..2047
    const int oh0   = strip * 16;
    const int ir0   = 2 * oh0 - 1;            // first input row of the strip

    const float* xp = x + (size_t)plane * (256 * 256);

    // ---- stage: 34 rows x 256 cols, fully coalesced float4 ----
    const int lin0 = tid << 2;                // 0..1020
    #pragma unroll
    for (int i = 0; i < 9; ++i) {
        int linear = i * 1024 + lin0;         // == r*256 + c
        int r = linear >> 8;
        if (r < 34) {
            int c  = linear & 255;
            int gr = ir0 + r;
            gr = (gr < 0) ? 1 : ((gr > 255) ? 254 : gr);   // reflect rows
            float4 v = *(const float4*)(xp + gr * 256 + c);
            *(float4*)(&lds[linear]) = v;
        }
    }
    __syncthreads();

    // ---- compute: thread = one output column, 8 output rows ----
    const int ow   = tid & 127;
    const int half = tid >> 7;                // 0: rows 0..7, 1: rows 8..15
    const float* L = lds + (half << 4) * 256; // LDS row offset 0 or 16

    // horizontal tap addresses; reflect only at ow==0 / ow==127 (2 lanes)
    const int c1 = 2 * ow;
    const float* pm = L + ((ow == 0)   ? 1   : c1 - 1);  // tap -1
    const float* p0 = L + c1;                            // taps 0,+1 (merge to read2)
    const float* pp = L + ((ow == 127) ? 254 : c1 + 2);  // tap +2

    auto H = [&](int lr) {
        int o = lr * 256;
        return K0 * pm[o] + K1 * p0[o] + K1 * p0[o + 1] + K0 * pp[o];
    };

    float* op = out + (size_t)plane * (128 * 128)
                    + (size_t)(oh0 + (half << 3)) * 128 + ow;

    float h0 = H(0);
    float h1 = H(1);
    #pragma unroll
    for (int l = 0; l < 8; ++l) {
        float h2 = H(2 * l + 2);
        float h3 = H(2 * l + 3);
        op[l * 128] = K0 * h0 + K1 * h1 + K1 * h2 + K0 * h3;
        h0 = h2;
        h1 = h3;
    }
}

extern "C" void kernel_launch(void* const* d_in, const int* in_sizes, int n_in,
                              void* d_out, int out_size, void* d_ws, size_t ws_size,
                              hipStream_t stream) {
    const float* x = (const float*)d_in[0];
    // d_in[1] is the 4x4 kernel == outer([1/8,3/8,3/8,1/8]) exactly; taps hardcoded.
    float* out = (float*)d_out;

    const int planes = 8 * 256;               // B*C
    const int blocks = planes * 8;            // 8 strips per plane
    downsample2d_kernel<<<blocks, 256, 0, stream>>>(x, out);
}